// Round 1
// 1022.335 us; speedup vs baseline: 1.1705x; 1.1705x over previous
//
#include <hip/hip_runtime.h>

// ---------------------------------------------------------------------------
// GPT-J attention on MI355X (gfx950), bf16 MFMA pipeline.
// B=2 S=2048 E=4096 H=16 D=256 ROT=64
// R4: both GEMMs upgraded to the 256x256 8-phase schedule (T2 swizzle +
//     T3/T4 counted-vmcnt pipeline + T5 setprio). 512 thr, 128 KiB LDS,
//     4 phases/K-tile, vmcnt(4) per tile boundary (never 0 in loop).
//     Wrap-staging keeps vmcnt arithmetic exact at the tail.
// ---------------------------------------------------------------------------

typedef __bf16 bf16;
typedef bf16  bf16x4 __attribute__((ext_vector_type(4)));
typedef bf16  bf16x8 __attribute__((ext_vector_type(8)));
typedef float f32x4  __attribute__((ext_vector_type(4)));

#define SEQ 2048
#define ED  4096
#define NH  16
#define HD  256

__device__ __forceinline__ void async_load16(const void* g, void* l) {
  __builtin_amdgcn_global_load_lds(
      (const __attribute__((address_space(1))) void*)g,
      (__attribute__((address_space(3))) void*)l, 16, 0, 0);
}

// ---------------------------------------------------------------------------
// fused fp32 -> bf16 conversion, 4 sources, 4 elems/thread
// ---------------------------------------------------------------------------
__global__ void cvt4_f32_bf16(const float* __restrict__ s0,
                              const float* __restrict__ s1,
                              const float* __restrict__ s2,
                              const float* __restrict__ s3,
                              bf16* __restrict__ d0, bf16* __restrict__ d1,
                              bf16* __restrict__ d2, bf16* __restrict__ d3) {
  int sec = blockIdx.x >> 14;              // 16384 blocks / section
  int idx = ((blockIdx.x & 16383) * 256 + threadIdx.x) * 4;
  const float* s = sec == 0 ? s0 : sec == 1 ? s1 : sec == 2 ? s2 : s3;
  bf16* d = sec == 0 ? d0 : sec == 1 ? d1 : sec == 2 ? d2 : d3;
  float4 v = *(const float4*)(s + idx);
  bf16x4 o;
  o.x = (bf16)v.x; o.y = (bf16)v.y; o.z = (bf16)v.z; o.w = (bf16)v.w;
  *(bf16x4*)(d + idx) = o;
}

__global__ void cvt_f32_bf16(const float* __restrict__ src,
                             bf16* __restrict__ dst, int n) {
  int idx = (blockIdx.x * 256 + threadIdx.x) * 4;
  if (idx < n) {
    float4 v = *(const float4*)(src + idx);
    bf16x4 o;
    o.x = (bf16)v.x; o.y = (bf16)v.y; o.z = (bf16)v.z; o.w = (bf16)v.w;
    *(bf16x4*)(dst + idx) = o;
  }
}

// ---------------------------------------------------------------------------
// 256x256 8-phase bt-GEMM.  C[m,n] = dot(A[m,:], W[n,:]), K = 4096.
// 512 threads = 8 waves (2 m x 4 n); per-wave C = 128x64 (8x4 frags).
// LDS: A/B tiles [256 rows][64 k] bf16, double buffered = 128 KiB.
// Swizzle: logical 16B chunk c of row r stored at phys chunk c^(r&7);
// staging writes linear LDS and pre-swizzles the GLOBAL source column.
//
// Phase q of tile t (quadrants nh-grouped: (mh,nh) = 00,10,01,11):
//   12 ds_read_b128 frags | stage one 2-load unit | bar | MFMA x16 | bar
// Stage schedule (region-deadness proven):
//   q0: (t+1).A rows{64-127,192-255}   q1: (t+1).B rows{r:(r>>5)&1==1}
//   q2: (t+2).B rows{(r>>5)&1==0}      q3: (t+2).A rows{0-63,128-191}
//   + s_waitcnt vmcnt(4) at q3 (2 units stay in flight across boundary).
// ---------------------------------------------------------------------------
__device__ __forceinline__ void stageA(const bf16* __restrict__ g, bf16* lds,
                                       int qoff, int w, int lane) {
#pragma unroll
  for (int j = 0; j < 2; ++j) {
    const int u0 = j * 64 + w * 8;
    const int rb = ((u0 >> 6) << 7) + qoff + (u0 & 63);   // wave's 8-row base
    const int r  = rb + (lane >> 3);
    const int gc = (lane & 7) ^ (r & 7);                  // inverse swizzle
    async_load16(g + (size_t)r * ED + gc * 8, lds + (size_t)rb * 64);
  }
}

__device__ __forceinline__ void stageB(const bf16* __restrict__ g, bf16* lds,
                                       int off, int w, int lane) {
#pragma unroll
  for (int j = 0; j < 2; ++j) {
    const int u0 = j * 64 + w * 8;
    const int rb = ((u0 >> 5) << 6) + off + (u0 & 31);
    const int r  = rb + (lane >> 3);
    const int gc = (lane & 7) ^ (r & 7);
    async_load16(g + (size_t)r * ED + gc * 8, lds + (size_t)rb * 64);
  }
}

#define GPHASE(MH, NH, STAGE_STMT, DO_WAIT)                                    \
  {                                                                            \
    bf16x8 afr[4][2], bfr[2][2];                                               \
    _Pragma("unroll") for (int mi = 0; mi < 4; ++mi) {                         \
      int row = wm * 128 + ((MH)*4 + mi) * 16 + lo;                            \
      _Pragma("unroll") for (int ks = 0; ks < 2; ++ks)                         \
        afr[mi][ks] = *(const bf16x8*)(At + row * 64 +                         \
                        ((((ks << 2) + hi) ^ (row & 7)) << 3));                \
    }                                                                          \
    _Pragma("unroll") for (int ni = 0; ni < 2; ++ni) {                         \
      int row = wn * 64 + ((NH)*2 + ni) * 16 + lo;                             \
      _Pragma("unroll") for (int ks = 0; ks < 2; ++ks)                         \
        bfr[ni][ks] = *(const bf16x8*)(Bt + row * 64 +                         \
                        ((((ks << 2) + hi) ^ (row & 7)) << 3));                \
    }                                                                          \
    STAGE_STMT;                                                                \
    asm volatile("" ::: "memory");                                             \
    __builtin_amdgcn_s_barrier();                                              \
    __builtin_amdgcn_s_setprio(1);                                             \
    _Pragma("unroll") for (int mi = 0; mi < 4; ++mi)                           \
      _Pragma("unroll") for (int ni = 0; ni < 2; ++ni)                         \
        _Pragma("unroll") for (int ks = 0; ks < 2; ++ks)                       \
          acc[(MH)*4 + mi][(NH)*2 + ni] =                                      \
              __builtin_amdgcn_mfma_f32_16x16x32_bf16(                         \
                  afr[mi][ks], bfr[ni][ks], acc[(MH)*4 + mi][(NH)*2 + ni],     \
                  0, 0, 0);                                                    \
    __builtin_amdgcn_s_setprio(0);                                             \
    if (DO_WAIT) asm volatile("s_waitcnt vmcnt(4)" ::: "memory");              \
    asm volatile("" ::: "memory");                                             \
    __builtin_amdgcn_s_barrier();                                              \
    asm volatile("" ::: "memory");                                             \
  }

template <int MODE>   // 0 = QKV epilogue (bf16 scatter), 1 = fp32 C
__device__ __forceinline__ void gemm256_body(
    char* smem, const bf16* __restrict__ A, const bf16* __restrict__ W,
    bf16* __restrict__ Qb, bf16* __restrict__ Kb, bf16* __restrict__ Vtmp,
    float* __restrict__ Cf) {
  const int tid = threadIdx.x;
  const int w = tid >> 6, lane = tid & 63;
  const int wm = w >> 2, wn = w & 3;
  const int lo = lane & 15, hi = lane >> 4;

  // XCD-bijective swizzle (grid % 8 == 0); tm fastest for per-XCD W reuse.
  const int nwg = gridDim.x;
  const int id = (blockIdx.x & 7) * (nwg >> 3) + (blockIdx.x >> 3);
  const int tm = id & 15, tn = id >> 4;

  const bf16* Ab = A + (size_t)tm * 256 * ED;
  const bf16* Wb = W + (size_t)tn * 256 * ED;

  bf16* A0 = (bf16*)smem;
  bf16* B0 = (bf16*)(smem + 32768);
  bf16* A1 = (bf16*)(smem + 65536);
  bf16* B1 = (bf16*)(smem + 98304);

  f32x4 acc[8][4] = {};

  // prologue: tile0 full -> buf0 (8 loads); tile1 Blow + Aq02 -> buf1 (4).
  stageA(Ab, A0, 0, w, lane);
  stageA(Ab, A0, 64, w, lane);
  stageB(Wb, B0, 0, w, lane);
  stageB(Wb, B0, 32, w, lane);
  stageB(Wb + 64, B1, 0, w, lane);
  stageA(Ab + 64, A1, 0, w, lane);
  asm volatile("s_waitcnt vmcnt(4)" ::: "memory");
  __builtin_amdgcn_s_barrier();
  asm volatile("" ::: "memory");

#pragma unroll 2
  for (int t = 0; t < 64; ++t) {
    const int cur = t & 1;
    bf16* At = cur ? A1 : A0;
    bf16* Bt = cur ? B1 : B0;
    bf16* An = cur ? A0 : A1;
    bf16* Bn = cur ? B0 : B1;
    // wrap-staged tile indices keep vmcnt counts exact at the tail; the
    // wrapped writes land only in dead regions and are never read.
    const bf16* gA1p = Ab + ((t + 1) & 63) * 64;
    const bf16* gW1p = Wb + ((t + 1) & 63) * 64;
    const bf16* gA2p = Ab + ((t + 2) & 63) * 64;
    const bf16* gW2p = Wb + ((t + 2) & 63) * 64;

    GPHASE(0, 0, stageA(gA1p, An, 64, w, lane), 0)  // (t+1) A rows 64-127/192-255
    GPHASE(1, 0, stageB(gW1p, Bn, 32, w, lane), 0)  // (t+1) B-high
    GPHASE(0, 1, stageB(gW2p, Bt, 0, w, lane), 0)   // (t+2) B-low (dead after q1)
    GPHASE(1, 1, stageA(gA2p, At, 0, w, lane), 1)   // (t+2) A rows 0-63/128-191
  }

  if (MODE == 0) {
    const int widx = tn >> 4;            // 0=Q 1=K 2=V
    const int f0 = (tn & 15) * 256;
    bf16* Ob = widx == 0 ? Qb : (widx == 1 ? Kb : Vtmp);
#pragma unroll
    for (int mi = 0; mi < 8; ++mi)
#pragma unroll
      for (int ni = 0; ni < 4; ++ni)
#pragma unroll
        for (int r = 0; r < 4; ++r) {
          int m = tm * 256 + wm * 128 + mi * 16 + hi * 4 + r;
          int f = f0 + wn * 64 + ni * 16 + lo;
          int b = m >> 11, s = m & 2047;
          int h = f >> 8, d = f & 255;
          Ob[(((size_t)(b * NH + h) * SEQ) + s) * HD + d] = (bf16)acc[mi][ni][r];
        }
  } else {
#pragma unroll
    for (int mi = 0; mi < 8; ++mi)
#pragma unroll
      for (int ni = 0; ni < 4; ++ni)
#pragma unroll
        for (int r = 0; r < 4; ++r) {
          int m = tm * 256 + wm * 128 + mi * 16 + hi * 4 + r;
          int n = tn * 256 + wn * 64 + ni * 16 + lo;
          Cf[(size_t)m * ED + n] = acc[mi][ni][r];
        }
  }
}

__global__ __launch_bounds__(512, 2) void gemm_qkv256(
    const bf16* __restrict__ A, const bf16* __restrict__ W,
    bf16* __restrict__ Qb, bf16* __restrict__ Kb, bf16* __restrict__ Vtmp) {
  extern __shared__ char smem[];
  gemm256_body<0>(smem, A, W, Qb, Kb, Vtmp, nullptr);
}

__global__ __launch_bounds__(512, 2) void gemm_out256(
    const bf16* __restrict__ A, const bf16* __restrict__ W,
    float* __restrict__ C) {
  extern __shared__ char smem[];
  gemm256_body<1>(smem, A, W, nullptr, nullptr, nullptr, C);
}

// ---------------------------------------------------------------------------
// V transpose: (b,h,s,d) -> (b,h,d,s). 64x64 tiles via padded LDS.
// ---------------------------------------------------------------------------
__global__ __launch_bounds__(256) void transpose_v(const bf16* __restrict__ src,
                                                   bf16* __restrict__ dst) {
  __shared__ bf16 T[64][72];
  const int bh = blockIdx.z;
  const int st = blockIdx.x;
  const int dt = blockIdx.y;
  const bf16* S = src + ((size_t)bh * SEQ + st * 64) * HD + dt * 64;
#pragma unroll
  for (int p = 0; p < 2; ++p) {
    int r = p * 32 + (threadIdx.x >> 3), c = (threadIdx.x & 7) * 8;
    *(bf16x8*)&T[r][c] = *(const bf16x8*)(S + (size_t)r * HD + c);
  }
  __syncthreads();
  bf16* D = dst + ((size_t)bh * HD + dt * 64) * SEQ + st * 64;
#pragma unroll
  for (int p = 0; p < 2; ++p) {
    int r = p * 32 + (threadIdx.x >> 3), c = (threadIdx.x & 7) * 8;
    bf16x8 v;
#pragma unroll
    for (int j = 0; j < 8; ++j) v[j] = T[c + j][r];
    *(bf16x8*)(D + (size_t)r * SEQ + c) = v;
  }
}

// ---------------------------------------------------------------------------
// RoPE, vectorized: one thread = 4 interleaved pairs (bf16x8, 16 B).
// ---------------------------------------------------------------------------
__global__ void rope_kernel(bf16* __restrict__ Qb, bf16* __restrict__ Kb,
                            const int* __restrict__ pos_ids,
                            const float* __restrict__ emb) {
  int idx = blockIdx.x * 256 + threadIdx.x;
  int g = idx & 7;
  int s = (idx >> 3) & 2047;
  int h = (idx >> 14) & 15;
  int b = (idx >> 18) & 1;
  int t = idx >> 19;
  bf16* T = t ? Kb : Qb;
  int pos = pos_ids[b * SEQ + s];
  const float* e = emb + pos * 64;
  size_t base = (((size_t)(b * NH + h) * SEQ) + s) * HD + g * 8;
  bf16x8 v = *(bf16x8*)(T + base);
  bf16x8 o;
#pragma unroll
  for (int j = 0; j < 4; ++j) {
    int p = g * 4 + j;
    float sn = e[p], cs = e[32 + p];
    float x0 = (float)v[2 * j], x1 = (float)v[2 * j + 1];
    o[2 * j]     = (bf16)(x0 * cs - x1 * sn);
    o[2 * j + 1] = (bf16)(x1 * cs + x0 * sn);
  }
  *(bf16x8*)(T + base) = o;
}

// ---------------------------------------------------------------------------
// Flash attention (causal), qt-paired for load balance. (unchanged)
// ---------------------------------------------------------------------------
__global__ __launch_bounds__(256) void attn_kernel(
    const bf16* __restrict__ Qb, const bf16* __restrict__ Kb,
    const bf16* __restrict__ Vt, bf16* __restrict__ AO) {
  __shared__ bf16 Ks[64 * 256];    // 32 KB
  __shared__ bf16 Vs[256 * 64];    // 32 KB
  __shared__ bf16 Ps[4 * 16 * 64]; // 8 KB, wave-private strips
  const int tid = threadIdx.x;
  const int w = tid >> 6, lane = tid & 63;
  const int lo = lane & 15, hi = lane >> 4;
  const int slot = blockIdx.x;  // 0..15
  const int bh = blockIdx.y;    // 0..31

  const bf16* Qh = Qb + (size_t)bh * SEQ * HD;
  const bf16* Kh = Kb + (size_t)bh * SEQ * HD;
  const bf16* Vh = Vt + (size_t)bh * HD * SEQ;
  const int b = bh >> 4, h = bh & 15;

  for (int half = 0; half < 2; ++half) {
    const int qt = half ? (31 - slot) : slot;

    bf16x8 aq[8];
    const int qrow = qt * 64 + w * 16 + lo;
#pragma unroll
    for (int ks = 0; ks < 8; ++ks)
      aq[ks] = *(const bf16x8*)(Qh + (size_t)qrow * HD + ks * 32 + hi * 8);

    f32x4 o[16] = {};
    float mrow[4], lrow[4];
#pragma unroll
    for (int r = 0; r < 4; ++r) { mrow[r] = -3e38f; lrow[r] = 0.f; }

    for (int kt = 0; kt <= qt; ++kt) {
#pragma unroll
      for (int i = 0; i < 8; ++i) {
        int ci = w * 8 + i;
        int r = ci * 2 + (lane >> 5);
        int cc = (lane & 31) ^ (r & 7);
        async_load16(Kh + ((size_t)(kt * 64 + r)) * HD + cc * 8, &Ks[ci * 512]);
      }
#pragma unroll
      for (int i = 0; i < 8; ++i) {
        int ci = w * 8 + i;
        int d = ci * 8 + (lane >> 3);
        int cc = (lane & 7) ^ (d & 7);
        async_load16(Vh + (size_t)d * SEQ + kt * 64 + cc * 8, &Vs[ci * 512]);
      }
      __syncthreads();

      float sv[4][4];
#pragma unroll
      for (int nt = 0; nt < 4; ++nt) {
        f32x4 sacc = {};
#pragma unroll
        for (int ks = 0; ks < 8; ++ks) {
          int row = nt * 16 + lo;
          bf16x8 bk = *(const bf16x8*)
              &Ks[row * HD + ((((ks << 2) + hi) ^ (row & 7)) << 3)];
          sacc = __builtin_amdgcn_mfma_f32_16x16x32_bf16(aq[ks], bk, sacc, 0, 0, 0);
        }
#pragma unroll
        for (int r = 0; r < 4; ++r) {
          float x = sacc[r] * 0.0625f;
          if (kt == qt) {
            int col = kt * 64 + nt * 16 + lo;
            int row = qt * 64 + w * 16 + hi * 4 + r;
            if (col > row) x = -1e30f;
          }
          sv[nt][r] = x;
        }
      }

      float alpha[4];
#pragma unroll
      for (int r = 0; r < 4; ++r) {
        float mx = fmaxf(fmaxf(sv[0][r], sv[1][r]), fmaxf(sv[2][r], sv[3][r]));
        mx = fmaxf(mx, __shfl_xor(mx, 1));
        mx = fmaxf(mx, __shfl_xor(mx, 2));
        mx = fmaxf(mx, __shfl_xor(mx, 4));
        mx = fmaxf(mx, __shfl_xor(mx, 8));
        float mnew = fmaxf(mrow[r], mx);
        alpha[r] = __expf(mrow[r] - mnew);
        mrow[r] = mnew;
        float sum = 0.f;
#pragma unroll
        for (int nt = 0; nt < 4; ++nt) {
          float p = __expf(sv[nt][r] - mnew);
          sv[nt][r] = p;
          sum += p;
        }
        sum += __shfl_xor(sum, 1);
        sum += __shfl_xor(sum, 2);
        sum += __shfl_xor(sum, 4);
        sum += __shfl_xor(sum, 8);
        lrow[r] = lrow[r] * alpha[r] + sum;
      }

#pragma unroll
      for (int nt2 = 0; nt2 < 16; ++nt2)
#pragma unroll
        for (int r = 0; r < 4; ++r) o[nt2][r] *= alpha[r];

#pragma unroll
      for (int nt = 0; nt < 4; ++nt)
#pragma unroll
        for (int r = 0; r < 4; ++r) {
          int prow = hi * 4 + r;
          int chunk = nt * 2 + (lo >> 3);
          Ps[w * 1024 + prow * 64 + (((chunk ^ (prow & 7)) << 3) | (lo & 7))] =
              (bf16)sv[nt][r];
        }
      bf16x8 pa[2];
#pragma unroll
      for (int k2 = 0; k2 < 2; ++k2)
        pa[k2] = *(const bf16x8*)
            &Ps[w * 1024 + lo * 64 + ((((k2 << 2) + hi) ^ (lo & 7)) << 3)];

#pragma unroll
      for (int nt2 = 0; nt2 < 16; ++nt2) {
#pragma unroll
        for (int k2 = 0; k2 < 2; ++k2) {
          int row = nt2 * 16 + lo;
          bf16x8 bv = *(const bf16x8*)
              &Vs[row * 64 + ((((k2 << 2) + hi) ^ (row & 7)) << 3)];
          o[nt2] = __builtin_amdgcn_mfma_f32_16x16x32_bf16(pa[k2], bv, o[nt2], 0, 0, 0);
        }
      }
      __syncthreads();
    }

#pragma unroll
    for (int r = 0; r < 4; ++r) {
      float inv = 1.f / lrow[r];
      int srow = qt * 64 + w * 16 + hi * 4 + r;
      size_t base = ((size_t)(b * SEQ + srow)) * ED + h * HD;
#pragma unroll
      for (int nt2 = 0; nt2 < 16; ++nt2)
        AO[base + nt2 * 16 + lo] = (bf16)(o[nt2][r] * inv);
    }
  }
}

// ---------------------------------------------------------------------------
// launch
// ---------------------------------------------------------------------------
extern "C" void kernel_launch(void* const* d_in, const int* in_sizes, int n_in,
                              void* d_out, int out_size, void* d_ws,
                              size_t ws_size, hipStream_t stream) {
  const float* hs  = (const float*)d_in[0];
  const int*   pos = (const int*)d_in[1];
  const float* qw  = (const float*)d_in[2];
  const float* kw  = (const float*)d_in[3];
  const float* vw  = (const float*)d_in[4];
  const float* ow  = (const float*)d_in[5];
  const float* emb = (const float*)d_in[6];
  float* out = (float*)d_out;

  char* ws = (char*)d_ws;
  const size_t MB = 1024 * 1024;
  bf16* Hb   = (bf16*)(ws);
  bf16* AO   = (bf16*)(ws);
  bf16* Wqkv = (bf16*)(ws + 32 * MB);
  bf16* Wo   = (bf16*)(ws + 32 * MB);
  bf16* Vt   = (bf16*)(ws + 64 * MB);
  bf16* Qb   = (bf16*)(ws + 128 * MB);
  bf16* Kb   = (bf16*)(ws + 160 * MB);
  bf16* Vtmp = (bf16*)(ws + 192 * MB);

  const int n = ED * ED;            // 16777216

  static bool s_attr = false;
  if (!s_attr) {
    hipFuncSetAttribute((const void*)gemm_qkv256,
                        hipFuncAttributeMaxDynamicSharedMemorySize, 131072);
    hipFuncSetAttribute((const void*)gemm_out256,
                        hipFuncAttributeMaxDynamicSharedMemorySize, 131072);
    s_attr = true;
  }

  cvt4_f32_bf16<<<65536, 256, 0, stream>>>(
      hs, qw, kw, vw, Hb, Wqkv, Wqkv + (size_t)n, Wqkv + 2 * (size_t)n);

  gemm_qkv256<<<768, 512, 131072, stream>>>(Hb, Wqkv, Qb, Kb, Vtmp);

  cvt_f32_bf16<<<16384, 256, 0, stream>>>(ow, Wo, n);
  transpose_v<<<dim3(32, 4, 32), 256, 0, stream>>>(Vtmp, Vt);

  rope_kernel<<<4096, 256, 0, stream>>>(Qb, Kb, pos, emb);

  attn_kernel<<<dim3(16, 32), 256, 0, stream>>>(Qb, Kb, Vt, AO);

  gemm_out256<<<256, 512, 131072, stream>>>(AO, Wo, out);
}

// Round 2
// 1013.368 us; speedup vs baseline: 1.1809x; 1.0088x over previous
//
#include <hip/hip_runtime.h>

// ---------------------------------------------------------------------------
// GPT-J attention on MI355X (gfx950), bf16 MFMA pipeline.
// B=2 S=2048 E=4096 H=16 D=256 ROT=64
// R5: GEMM phases reordered to serpentine quadrants (0,0)->(0,1)->(1,1)->(1,0)
//     with fragment reuse in registers: 24 ds_read_b128 per K-tile per wave
//     (was 48 -- the R4 kernel was LDS-read-BW bound at MfmaUtil 44%).
//     Deeper stage pipeline: 1 unit/phase, vmcnt(6)@q0 / vmcnt(8)@q3,
//     up to 12 loads in flight, never drained in-loop.
// ---------------------------------------------------------------------------

typedef __bf16 bf16;
typedef bf16  bf16x4 __attribute__((ext_vector_type(4)));
typedef bf16  bf16x8 __attribute__((ext_vector_type(8)));
typedef float f32x4  __attribute__((ext_vector_type(4)));

#define SEQ 2048
#define ED  4096
#define NH  16
#define HD  256

__device__ __forceinline__ void async_load16(const void* g, void* l) {
  __builtin_amdgcn_global_load_lds(
      (const __attribute__((address_space(1))) void*)g,
      (__attribute__((address_space(3))) void*)l, 16, 0, 0);
}

// ---------------------------------------------------------------------------
// fused fp32 -> bf16 conversion, 4 sources, 4 elems/thread
// ---------------------------------------------------------------------------
__global__ void cvt4_f32_bf16(const float* __restrict__ s0,
                              const float* __restrict__ s1,
                              const float* __restrict__ s2,
                              const float* __restrict__ s3,
                              bf16* __restrict__ d0, bf16* __restrict__ d1,
                              bf16* __restrict__ d2, bf16* __restrict__ d3) {
  int sec = blockIdx.x >> 14;              // 16384 blocks / section
  int idx = ((blockIdx.x & 16383) * 256 + threadIdx.x) * 4;
  const float* s = sec == 0 ? s0 : sec == 1 ? s1 : sec == 2 ? s2 : s3;
  bf16* d = sec == 0 ? d0 : sec == 1 ? d1 : sec == 2 ? d2 : d3;
  float4 v = *(const float4*)(s + idx);
  bf16x4 o;
  o.x = (bf16)v.x; o.y = (bf16)v.y; o.z = (bf16)v.z; o.w = (bf16)v.w;
  *(bf16x4*)(d + idx) = o;
}

__global__ void cvt_f32_bf16(const float* __restrict__ src,
                             bf16* __restrict__ dst, int n) {
  int idx = (blockIdx.x * 256 + threadIdx.x) * 4;
  if (idx < n) {
    float4 v = *(const float4*)(src + idx);
    bf16x4 o;
    o.x = (bf16)v.x; o.y = (bf16)v.y; o.z = (bf16)v.z; o.w = (bf16)v.w;
    *(bf16x4*)(dst + idx) = o;
  }
}

// ---------------------------------------------------------------------------
// 256x256 8-phase bt-GEMM.  C[m,n] = dot(A[m,:], W[n,:]), K = 4096.
// 512 threads = 8 waves (2 m x 4 n); per-wave C = 128x64 (8x4 frags).
// LDS: A/B tiles [256 rows][64 k] bf16, double buffered = 128 KiB.
// Swizzle: logical 16B chunk c of row r stored at phys chunk c^(r&7);
// staging writes linear LDS and pre-swizzles the GLOBAL source column.
//
// Serpentine phases per K-tile t (each frag read from LDS exactly once):
//   q0: read A-lo + B-lo (12 b128) | stage A-hi(t+1)->next | MFMA (0,0)
//       | vmcnt(6) | bar
//   q1: read B-hi (4)              | stage B-hi(t+1)->next | MFMA (0,1) | bar
//   q2: read A-hi (8, reuse regs)  | stage B-lo(t+2)->cur  | MFMA (1,1) | bar
//   q3: (no reads)                 | stage A-lo(t+2)->cur  | MFMA (1,0)
//       | vmcnt(8) | bar
// Deadness: A-lo/B-lo dead after q0, B-hi after q1, A-hi after q2; next
// buffer fully dead. vmcnt(6)@q0 retires B-hi(t) (and A-hi(t)) for q1/q2;
// vmcnt(8)@q3 retires A-lo/B-lo(t+1) for t+1.q0. Max 12 loads in flight.
// ---------------------------------------------------------------------------
__device__ __forceinline__ void stageA(const bf16* __restrict__ g, bf16* lds,
                                       int qoff, int w, int lane) {
#pragma unroll
  for (int j = 0; j < 2; ++j) {
    const int u0 = j * 64 + w * 8;
    const int rb = ((u0 >> 6) << 7) + qoff + (u0 & 63);   // wave's 8-row base
    const int r  = rb + (lane >> 3);
    const int gc = (lane & 7) ^ (r & 7);                  // inverse swizzle
    async_load16(g + (size_t)r * ED + gc * 8, lds + (size_t)rb * 64);
  }
}

__device__ __forceinline__ void stageB(const bf16* __restrict__ g, bf16* lds,
                                       int off, int w, int lane) {
#pragma unroll
  for (int j = 0; j < 2; ++j) {
    const int u0 = j * 64 + w * 8;
    const int rb = ((u0 >> 5) << 6) + off + (u0 & 31);
    const int r  = rb + (lane >> 3);
    const int gc = (lane & 7) ^ (r & 7);
    async_load16(g + (size_t)r * ED + gc * 8, lds + (size_t)rb * 64);
  }
}

#define BARRIER()                                                              \
  do {                                                                         \
    asm volatile("" ::: "memory");                                             \
    __builtin_amdgcn_s_barrier();                                              \
    asm volatile("" ::: "memory");                                             \
  } while (0)

#define LDF_A(dst, Abuf, MH)                                                   \
  _Pragma("unroll") for (int mi = 0; mi < 4; ++mi) {                           \
    const int row_ = wm * 128 + ((MH) * 4 + mi) * 16 + lo;                     \
    _Pragma("unroll") for (int ks = 0; ks < 2; ++ks)                           \
      dst[mi][ks] = *(const bf16x8*)((Abuf) + row_ * 64 +                      \
                      ((((ks << 2) + hi) ^ (row_ & 7)) << 3));                 \
  }

#define LDF_B(dst, Bbuf, NHQ)                                                  \
  _Pragma("unroll") for (int ni = 0; ni < 2; ++ni) {                           \
    const int row_ = wn * 64 + ((NHQ) * 2 + ni) * 16 + lo;                     \
    _Pragma("unroll") for (int ks = 0; ks < 2; ++ks)                           \
      dst[ni][ks] = *(const bf16x8*)((Bbuf) + row_ * 64 +                      \
                      ((((ks << 2) + hi) ^ (row_ & 7)) << 3));                 \
  }

#define MFMA_Q(af, bv, MH, NHQ)                                                \
  do {                                                                         \
    __builtin_amdgcn_s_setprio(1);                                             \
    _Pragma("unroll") for (int mi = 0; mi < 4; ++mi)                           \
      _Pragma("unroll") for (int ni = 0; ni < 2; ++ni)                         \
        _Pragma("unroll") for (int ks = 0; ks < 2; ++ks)                       \
          acc[(MH) * 4 + mi][(NHQ) * 2 + ni] =                                 \
              __builtin_amdgcn_mfma_f32_16x16x32_bf16(                         \
                  af[mi][ks], bv[ni][ks],                                      \
                  acc[(MH) * 4 + mi][(NHQ) * 2 + ni], 0, 0, 0);                \
    __builtin_amdgcn_s_setprio(0);                                             \
  } while (0)

template <int MODE>   // 0 = QKV epilogue (bf16 scatter), 1 = fp32 C
__device__ __forceinline__ void gemm256_body(
    char* smem, const bf16* __restrict__ A, const bf16* __restrict__ W,
    bf16* __restrict__ Qb, bf16* __restrict__ Kb, bf16* __restrict__ Vtmp,
    float* __restrict__ Cf) {
  const int tid = threadIdx.x;
  const int w = tid >> 6, lane = tid & 63;
  const int wm = w >> 2, wn = w & 3;
  const int lo = lane & 15, hi = lane >> 4;

  // XCD-bijective swizzle (grid % 8 == 0); tm fastest for per-XCD W reuse.
  const int nwg = gridDim.x;
  const int id = (blockIdx.x & 7) * (nwg >> 3) + (blockIdx.x >> 3);
  const int tm = id & 15, tn = id >> 4;

  const bf16* Ab = A + (size_t)tm * 256 * ED;
  const bf16* Wb = W + (size_t)tn * 256 * ED;

  bf16* A0 = (bf16*)smem;
  bf16* B0 = (bf16*)(smem + 32768);
  bf16* A1 = (bf16*)(smem + 65536);
  bf16* B1 = (bf16*)(smem + 98304);

  f32x4 acc[8][4] = {};
  bf16x8 a[4][2], b0[2][2], b1[2][2];

  // prologue: issue order must match steady-state roles
  // (t-1.q0: A-hi, t-1.q1: B-hi, t-1.q2: B-lo(next), t-1.q3: A-lo(next)).
  stageA(Ab, A0, 0, w, lane);       // A-lo(0)   (retired by vmcnt(8))
  stageB(Wb, B0, 0, w, lane);       // B-lo(0)   (retired by vmcnt(8))
  stageA(Ab, A0, 64, w, lane);      // A-hi(0)
  stageB(Wb, B0, 32, w, lane);      // B-hi(0)
  stageB(Wb + 64, B1, 0, w, lane);  // B-lo(1)
  stageA(Ab + 64, A1, 0, w, lane);  // A-lo(1)
  asm volatile("s_waitcnt vmcnt(8)" ::: "memory");
  BARRIER();

#pragma unroll 2
  for (int t = 0; t < 64; ++t) {
    const int cur = t & 1;
    bf16* At = cur ? A1 : A0;
    bf16* Bt = cur ? B1 : B0;
    bf16* An = cur ? A0 : A1;
    bf16* Bn = cur ? B0 : B1;
    // wrap-staged tile indices keep vmcnt counts exact at the tail; the
    // wrapped writes land only in dead regions and are never read.
    const bf16* gA1p = Ab + ((t + 1) & 63) * 64;
    const bf16* gW1p = Wb + ((t + 1) & 63) * 64;
    const bf16* gA2p = Ab + ((t + 2) & 63) * 64;
    const bf16* gW2p = Wb + ((t + 2) & 63) * 64;

    // ---- q0: quadrant (0,0) ----
    LDF_A(a, At, 0);
    LDF_B(b0, Bt, 0);
    stageA(gA1p, An, 64, w, lane);        // A-hi(t+1)
    BARRIER();
    MFMA_Q(a, b0, 0, 0);
    asm volatile("s_waitcnt vmcnt(6)" ::: "memory");  // retires B-hi(t), A-hi(t)
    BARRIER();

    // ---- q1: quadrant (0,1), reuse A-lo regs ----
    LDF_B(b1, Bt, 1);
    stageB(gW1p, Bn, 32, w, lane);        // B-hi(t+1)
    BARRIER();
    MFMA_Q(a, b1, 0, 1);
    BARRIER();

    // ---- q2: quadrant (1,1), reuse B-hi regs; A regs reloaded ----
    LDF_A(a, At, 1);
    stageB(gW2p, Bt, 0, w, lane);         // B-lo(t+2) into cur (dead since q0)
    BARRIER();
    MFMA_Q(a, b1, 1, 1);
    BARRIER();

    // ---- q3: quadrant (1,0), reuse A-hi + B-lo regs ----
    stageA(gA2p, At, 0, w, lane);         // A-lo(t+2) into cur (dead since q0)
    BARRIER();
    MFMA_Q(a, b0, 1, 0);
    asm volatile("s_waitcnt vmcnt(8)" ::: "memory");  // retires A/B-lo(t+1)
    BARRIER();
  }

  if (MODE == 0) {
    const int widx = tn >> 4;            // 0=Q 1=K 2=V
    const int f0 = (tn & 15) * 256;
    bf16* Ob = widx == 0 ? Qb : (widx == 1 ? Kb : Vtmp);
#pragma unroll
    for (int mi = 0; mi < 8; ++mi)
#pragma unroll
      for (int ni = 0; ni < 4; ++ni)
#pragma unroll
        for (int r = 0; r < 4; ++r) {
          int m = tm * 256 + wm * 128 + mi * 16 + hi * 4 + r;
          int f = f0 + wn * 64 + ni * 16 + lo;
          int b = m >> 11, s = m & 2047;
          int h = f >> 8, d = f & 255;
          Ob[(((size_t)(b * NH + h) * SEQ) + s) * HD + d] = (bf16)acc[mi][ni][r];
        }
  } else {
#pragma unroll
    for (int mi = 0; mi < 8; ++mi)
#pragma unroll
      for (int ni = 0; ni < 4; ++ni)
#pragma unroll
        for (int r = 0; r < 4; ++r) {
          int m = tm * 256 + wm * 128 + mi * 16 + hi * 4 + r;
          int n = tn * 256 + wn * 64 + ni * 16 + lo;
          Cf[(size_t)m * ED + n] = acc[mi][ni][r];
        }
  }
}

__global__ __launch_bounds__(512, 2) void gemm_qkv256(
    const bf16* __restrict__ A, const bf16* __restrict__ W,
    bf16* __restrict__ Qb, bf16* __restrict__ Kb, bf16* __restrict__ Vtmp) {
  extern __shared__ char smem[];
  gemm256_body<0>(smem, A, W, Qb, Kb, Vtmp, nullptr);
}

__global__ __launch_bounds__(512, 2) void gemm_out256(
    const bf16* __restrict__ A, const bf16* __restrict__ W,
    float* __restrict__ C) {
  extern __shared__ char smem[];
  gemm256_body<1>(smem, A, W, nullptr, nullptr, nullptr, C);
}

// ---------------------------------------------------------------------------
// V transpose: (b,h,s,d) -> (b,h,d,s). 64x64 tiles via padded LDS.
// ---------------------------------------------------------------------------
__global__ __launch_bounds__(256) void transpose_v(const bf16* __restrict__ src,
                                                   bf16* __restrict__ dst) {
  __shared__ bf16 T[64][72];
  const int bh = blockIdx.z;
  const int st = blockIdx.x;
  const int dt = blockIdx.y;
  const bf16* S = src + ((size_t)bh * SEQ + st * 64) * HD + dt * 64;
#pragma unroll
  for (int p = 0; p < 2; ++p) {
    int r = p * 32 + (threadIdx.x >> 3), c = (threadIdx.x & 7) * 8;
    *(bf16x8*)&T[r][c] = *(const bf16x8*)(S + (size_t)r * HD + c);
  }
  __syncthreads();
  bf16* D = dst + ((size_t)bh * HD + dt * 64) * SEQ + st * 64;
#pragma unroll
  for (int p = 0; p < 2; ++p) {
    int r = p * 32 + (threadIdx.x >> 3), c = (threadIdx.x & 7) * 8;
    bf16x8 v;
#pragma unroll
    for (int j = 0; j < 8; ++j) v[j] = T[c + j][r];
    *(bf16x8*)(D + (size_t)r * SEQ + c) = v;
  }
}

// ---------------------------------------------------------------------------
// RoPE, vectorized: one thread = 4 interleaved pairs (bf16x8, 16 B).
// ---------------------------------------------------------------------------
__global__ void rope_kernel(bf16* __restrict__ Qb, bf16* __restrict__ Kb,
                            const int* __restrict__ pos_ids,
                            const float* __restrict__ emb) {
  int idx = blockIdx.x * 256 + threadIdx.x;
  int g = idx & 7;
  int s = (idx >> 3) & 2047;
  int h = (idx >> 14) & 15;
  int b = (idx >> 18) & 1;
  int t = idx >> 19;
  bf16* T = t ? Kb : Qb;
  int pos = pos_ids[b * SEQ + s];
  const float* e = emb + pos * 64;
  size_t base = (((size_t)(b * NH + h) * SEQ) + s) * HD + g * 8;
  bf16x8 v = *(bf16x8*)(T + base);
  bf16x8 o;
#pragma unroll
  for (int j = 0; j < 4; ++j) {
    int p = g * 4 + j;
    float sn = e[p], cs = e[32 + p];
    float x0 = (float)v[2 * j], x1 = (float)v[2 * j + 1];
    o[2 * j]     = (bf16)(x0 * cs - x1 * sn);
    o[2 * j + 1] = (bf16)(x1 * cs + x0 * sn);
  }
  *(bf16x8*)(T + base) = o;
}

// ---------------------------------------------------------------------------
// Flash attention (causal), qt-paired for load balance. (unchanged)
// ---------------------------------------------------------------------------
__global__ __launch_bounds__(256) void attn_kernel(
    const bf16* __restrict__ Qb, const bf16* __restrict__ Kb,
    const bf16* __restrict__ Vt, bf16* __restrict__ AO) {
  __shared__ bf16 Ks[64 * 256];    // 32 KB
  __shared__ bf16 Vs[256 * 64];    // 32 KB
  __shared__ bf16 Ps[4 * 16 * 64]; // 8 KB, wave-private strips
  const int tid = threadIdx.x;
  const int w = tid >> 6, lane = tid & 63;
  const int lo = lane & 15, hi = lane >> 4;
  const int slot = blockIdx.x;  // 0..15
  const int bh = blockIdx.y;    // 0..31

  const bf16* Qh = Qb + (size_t)bh * SEQ * HD;
  const bf16* Kh = Kb + (size_t)bh * SEQ * HD;
  const bf16* Vh = Vt + (size_t)bh * HD * SEQ;
  const int b = bh >> 4, h = bh & 15;

  for (int half = 0; half < 2; ++half) {
    const int qt = half ? (31 - slot) : slot;

    bf16x8 aq[8];
    const int qrow = qt * 64 + w * 16 + lo;
#pragma unroll
    for (int ks = 0; ks < 8; ++ks)
      aq[ks] = *(const bf16x8*)(Qh + (size_t)qrow * HD + ks * 32 + hi * 8);

    f32x4 o[16] = {};
    float mrow[4], lrow[4];
#pragma unroll
    for (int r = 0; r < 4; ++r) { mrow[r] = -3e38f; lrow[r] = 0.f; }

    for (int kt = 0; kt <= qt; ++kt) {
#pragma unroll
      for (int i = 0; i < 8; ++i) {
        int ci = w * 8 + i;
        int r = ci * 2 + (lane >> 5);
        int cc = (lane & 31) ^ (r & 7);
        async_load16(Kh + ((size_t)(kt * 64 + r)) * HD + cc * 8, &Ks[ci * 512]);
      }
#pragma unroll
      for (int i = 0; i < 8; ++i) {
        int ci = w * 8 + i;
        int d = ci * 8 + (lane >> 3);
        int cc = (lane & 7) ^ (d & 7);
        async_load16(Vh + (size_t)d * SEQ + kt * 64 + cc * 8, &Vs[ci * 512]);
      }
      __syncthreads();

      float sv[4][4];
#pragma unroll
      for (int nt = 0; nt < 4; ++nt) {
        f32x4 sacc = {};
#pragma unroll
        for (int ks = 0; ks < 8; ++ks) {
          int row = nt * 16 + lo;
          bf16x8 bk = *(const bf16x8*)
              &Ks[row * HD + ((((ks << 2) + hi) ^ (row & 7)) << 3)];
          sacc = __builtin_amdgcn_mfma_f32_16x16x32_bf16(aq[ks], bk, sacc, 0, 0, 0);
        }
#pragma unroll
        for (int r = 0; r < 4; ++r) {
          float x = sacc[r] * 0.0625f;
          if (kt == qt) {
            int col = kt * 64 + nt * 16 + lo;
            int row = qt * 64 + w * 16 + hi * 4 + r;
            if (col > row) x = -1e30f;
          }
          sv[nt][r] = x;
        }
      }

      float alpha[4];
#pragma unroll
      for (int r = 0; r < 4; ++r) {
        float mx = fmaxf(fmaxf(sv[0][r], sv[1][r]), fmaxf(sv[2][r], sv[3][r]));
        mx = fmaxf(mx, __shfl_xor(mx, 1));
        mx = fmaxf(mx, __shfl_xor(mx, 2));
        mx = fmaxf(mx, __shfl_xor(mx, 4));
        mx = fmaxf(mx, __shfl_xor(mx, 8));
        float mnew = fmaxf(mrow[r], mx);
        alpha[r] = __expf(mrow[r] - mnew);
        mrow[r] = mnew;
        float sum = 0.f;
#pragma unroll
        for (int nt = 0; nt < 4; ++nt) {
          float p = __expf(sv[nt][r] - mnew);
          sv[nt][r] = p;
          sum += p;
        }
        sum += __shfl_xor(sum, 1);
        sum += __shfl_xor(sum, 2);
        sum += __shfl_xor(sum, 4);
        sum += __shfl_xor(sum, 8);
        lrow[r] = lrow[r] * alpha[r] + sum;
      }

#pragma unroll
      for (int nt2 = 0; nt2 < 16; ++nt2)
#pragma unroll
        for (int r = 0; r < 4; ++r) o[nt2][r] *= alpha[r];

#pragma unroll
      for (int nt = 0; nt < 4; ++nt)
#pragma unroll
        for (int r = 0; r < 4; ++r) {
          int prow = hi * 4 + r;
          int chunk = nt * 2 + (lo >> 3);
          Ps[w * 1024 + prow * 64 + (((chunk ^ (prow & 7)) << 3) | (lo & 7))] =
              (bf16)sv[nt][r];
        }
      bf16x8 pa[2];
#pragma unroll
      for (int k2 = 0; k2 < 2; ++k2)
        pa[k2] = *(const bf16x8*)
            &Ps[w * 1024 + lo * 64 + ((((k2 << 2) + hi) ^ (lo & 7)) << 3)];

#pragma unroll
      for (int nt2 = 0; nt2 < 16; ++nt2) {
#pragma unroll
        for (int k2 = 0; k2 < 2; ++k2) {
          int row = nt2 * 16 + lo;
          bf16x8 bv = *(const bf16x8*)
              &Vs[row * 64 + ((((k2 << 2) + hi) ^ (row & 7)) << 3)];
          o[nt2] = __builtin_amdgcn_mfma_f32_16x16x32_bf16(pa[k2], bv, o[nt2], 0, 0, 0);
        }
      }
      __syncthreads();
    }

#pragma unroll
    for (int r = 0; r < 4; ++r) {
      float inv = 1.f / lrow[r];
      int srow = qt * 64 + w * 16 + hi * 4 + r;
      size_t base = ((size_t)(b * SEQ + srow)) * ED + h * HD;
#pragma unroll
      for (int nt2 = 0; nt2 < 16; ++nt2)
        AO[base + nt2 * 16 + lo] = (bf16)(o[nt2][r] * inv);
    }
  }
}

// ---------------------------------------------------------------------------
// launch
// ---------------------------------------------------------------------------
extern "C" void kernel_launch(void* const* d_in, const int* in_sizes, int n_in,
                              void* d_out, int out_size, void* d_ws,
                              size_t ws_size, hipStream_t stream) {
  const float* hs  = (const float*)d_in[0];
  const int*   pos = (const int*)d_in[1];
  const float* qw  = (const float*)d_in[2];
  const float* kw  = (const float*)d_in[3];
  const float* vw  = (const float*)d_in[4];
  const float* ow  = (const float*)d_in[5];
  const float* emb = (const float*)d_in[6];
  float* out = (float*)d_out;

  char* ws = (char*)d_ws;
  const size_t MB = 1024 * 1024;
  bf16* Hb   = (bf16*)(ws);
  bf16* AO   = (bf16*)(ws);
  bf16* Wqkv = (bf16*)(ws + 32 * MB);
  bf16* Wo   = (bf16*)(ws + 32 * MB);
  bf16* Vt   = (bf16*)(ws + 64 * MB);
  bf16* Qb   = (bf16*)(ws + 128 * MB);
  bf16* Kb   = (bf16*)(ws + 160 * MB);
  bf16* Vtmp = (bf16*)(ws + 192 * MB);

  const int n = ED * ED;            // 16777216

  static bool s_attr = false;
  if (!s_attr) {
    hipFuncSetAttribute((const void*)gemm_qkv256,
                        hipFuncAttributeMaxDynamicSharedMemorySize, 131072);
    hipFuncSetAttribute((const void*)gemm_out256,
                        hipFuncAttributeMaxDynamicSharedMemorySize, 131072);
    s_attr = true;
  }

  cvt4_f32_bf16<<<65536, 256, 0, stream>>>(
      hs, qw, kw, vw, Hb, Wqkv, Wqkv + (size_t)n, Wqkv + 2 * (size_t)n);

  gemm_qkv256<<<768, 512, 131072, stream>>>(Hb, Wqkv, Qb, Kb, Vtmp);

  cvt_f32_bf16<<<16384, 256, 0, stream>>>(ow, Wo, n);
  transpose_v<<<dim3(32, 4, 32), 256, 0, stream>>>(Vtmp, Vt);

  rope_kernel<<<4096, 256, 0, stream>>>(Qb, Kb, pos, emb);

  attn_kernel<<<dim3(16, 32), 256, 0, stream>>>(Qb, Kb, Vt, AO);

  gemm_out256<<<256, 512, 131072, stream>>>(AO, Wo, out);
}